// Round 4
// baseline (1917.808 us; speedup 1.0000x reference)
//
#include <hip/hip_runtime.h>
#include <hip/hip_bf16.h>

#define T_STEPS 512
#define BATCH   256
#define DIM     256
#define HID     256
#define NGRP    16   // row groups (16 rows each)
#define NS      4    // col-WGs per group

using bf16x8  = __attribute__((ext_vector_type(8))) __bf16;
using floatx4 = __attribute__((ext_vector_type(4))) float;

__device__ __forceinline__ float sigf(float x)   { return 1.0f / (1.0f + __expf(-x)); }
__device__ __forceinline__ float tanh_f(float x) { return 1.0f - 2.0f / (1.0f + __expf(2.0f * x)); }

__device__ __forceinline__ bf16x8 cvt8(const float* p) {
  floatx4 a = *(const floatx4*)p;
  floatx4 b = *(const floatx4*)(p + 4);
  bf16x8 r;
  r[0]=(__bf16)a[0]; r[1]=(__bf16)a[1]; r[2]=(__bf16)a[2]; r[3]=(__bf16)a[3];
  r[4]=(__bf16)b[0]; r[5]=(__bf16)b[1]; r[6]=(__bf16)b[2]; r[7]=(__bf16)b[3];
  return r;
}

__global__ void init_ws(int* __restrict__ bar) { bar[threadIdx.x] = 0; }

// 64 WGs x 512 thr: blockIdx = g + 16*s. Group g = 16 batch rows; col-WG s
// owns 64 h-cols (all 4 gates). Per wave: 2 gate-tiles, K=256, weights
// resident (128 VGPR). h exchanged among 4 same-XCD WGs via L3 mailbox with
// relaxed agent atomics; vmcnt(0) covers only the mailbox store; out stores
// issued after the flag. x-MFMAs run before the poll to hide exchange latency.
__global__ __launch_bounds__(512, 2) void lstm_s4(
    const float* __restrict__ x, const float* __restrict__ h0,
    const float* __restrict__ c0,
    const float* __restrict__ mask_x, const float* __restrict__ mask_h,
    const float* __restrict__ W_ih, const float* __restrict__ W_hh,
    const float* __restrict__ b_ih, const float* __restrict__ b_hh,
    const int* __restrict__ bs_g,
    float* __restrict__ out, float* __restrict__ hn_out, float* __restrict__ cn_out,
    int* __restrict__ flg, float* __restrict__ mb) {

  const int tid  = threadIdx.x;
  const int g    = blockIdx.x & 15;   // (g+16s)%8 == g%8 -> same XCD under round-robin
  const int s    = blockIdx.x >> 4;
  const int row_base = g * 16;
  const int lane = tid & 63;
  const int w    = tid >> 6;          // wave 0..7
  const int l15  = lane & 15;
  const int l4   = lane >> 4;

  // MFMA ownership: gate q, 2 col-tiles at cB
  const int q  = w >> 1;
  const int cB = s * 64 + (w & 1) * 32;

  // staging map: (srow, 8 cols at scb)
  const int srow = tid & 15;
  const int scb  = (tid >> 4) * 8;

  // cell map: (crow, cols colL0 and colL0+32 within WG's 64)
  const int crow  = tid >> 5;
  const int colL0 = tid & 31;

  __shared__ alignas(16) __bf16 s_x[16 * 256];      // 8 KB swizzled
  __shared__ alignas(16) __bf16 s_h[16 * 256];      // 8 KB swizzled
  __shared__ float s_gates[256 * 17];               // padded+swizzled
  __shared__ int s_bs[T_STEPS];

  for (int i = tid; i < T_STEPS; i += 512) s_bs[i] = bs_g[i];

  // ---- resident weights: 2 tiles x 8 ksteps x 2 mats = 128 VGPR ----
  bf16x8 wih_r[16], whh_r[16];
  #pragma unroll
  for (int tt = 0; tt < 2; ++tt) {
    const size_t wr = (size_t)(q * HID + cB + tt * 16 + l15) * DIM;
    #pragma unroll
    for (int m = 0; m < 8; ++m) {
      wih_r[tt * 8 + m] = cvt8(W_ih + wr + m * 32 + l4 * 8);
      whh_r[tt * 8 + m] = cvt8(W_hh + wr + m * 32 + l4 * 8);
    }
  }

  // staging masks (8 cols)
  floatx4 mxs[2], mhs[2];
  mxs[0] = *(const floatx4*)(mask_x + (row_base + srow) * DIM + scb);
  mxs[1] = *(const floatx4*)(mask_x + (row_base + srow) * DIM + scb + 4);
  mhs[0] = *(const floatx4*)(mask_h + (row_base + srow) * HID + scb);
  mhs[1] = *(const floatx4*)(mask_h + (row_base + srow) * HID + scb + 4);

  // cell biases / state
  float bb[4][2], c_[2], h_[2];
  #pragma unroll
  for (int qq = 0; qq < 4; ++qq) {
    bb[qq][0] = b_ih[qq * HID + s * 64 + colL0]      + b_hh[qq * HID + s * 64 + colL0];
    bb[qq][1] = b_ih[qq * HID + s * 64 + colL0 + 32] + b_hh[qq * HID + s * 64 + colL0 + 32];
  }
  c_[0] = c0[(row_base + crow) * HID + s * 64 + colL0];
  c_[1] = c0[(row_base + crow) * HID + s * 64 + colL0 + 32];
  h_[0] = h0[(row_base + crow) * HID + s * 64 + colL0];
  h_[1] = h0[(row_base + crow) * HID + s * 64 + colL0 + 32];

  // prologue staging of s_h(0), s_x(0)
  const int soff = ((srow * 512 + scb * 2) ^ ((srow & 7) << 4));
  {
    float v[8];
    floatx4 h0a = *(const floatx4*)(h0 + (row_base + srow) * HID + scb);
    floatx4 h0b = *(const floatx4*)(h0 + (row_base + srow) * HID + scb + 4);
    #pragma unroll
    for (int e = 0; e < 4; ++e) { v[e] = h0a[e] * mhs[0][e]; v[4+e] = h0b[e] * mhs[1][e]; }
    bf16x8 hb;
    #pragma unroll
    for (int e = 0; e < 8; ++e) hb[e] = (__bf16)v[e];
    *(bf16x8*)((char*)s_h + soff) = hb;

    floatx4 x0a = *(const floatx4*)(x + (size_t)(row_base + srow) * DIM + scb);
    floatx4 x0b = *(const floatx4*)(x + (size_t)(row_base + srow) * DIM + scb + 4);
    #pragma unroll
    for (int e = 0; e < 4; ++e) { v[e] = x0a[e] * mxs[0][e]; v[4+e] = x0b[e] * mxs[1][e]; }
    bf16x8 xb;
    #pragma unroll
    for (int e = 0; e < 8; ++e) xb[e] = (__bf16)v[e];
    *(bf16x8*)((char*)s_x + soff) = xb;
  }
  __syncthreads();   // prologue only

  const int aswz = (l15 & 7) << 4;
  const int ab0  = l15 * 512 + l4 * 16;

  int* flgp = flg + g * 32;

  for (int t = 0; t < T_STEPS; ++t) {
    const int bszt = s_bs[t];
    if (bszt <= row_base) {
      // group retired (bs non-increasing): zero out, no barriers ever again
      float* op = out + (size_t)t * (BATCH * HID) + (row_base + crow) * HID + s * 64;
      op[colL0] = 0.0f; op[colL0 + 32] = 0.0f;
      continue;
    }
    const bool act_n = (t + 1 < T_STEPS) && (s_bs[t + 1] > row_base);

    // A: prefetch x(t+1)
    floatx4 xpf0, xpf1;
    if (act_n) {
      const float* xp = x + ((size_t)(t + 1) * BATCH + row_base + srow) * DIM + scb;
      xpf0 = *(const floatx4*)xp;
      xpf1 = *(const floatx4*)(xp + 4);
    }

    // B: x-MFMAs (s_x staged last iter) — runs while partners finish
    floatx4 a0, a1;
    a0 = a1 = (floatx4)(0.0f);
    #pragma unroll
    for (int m = 0; m < 8; ++m) {
      const int ab = (ab0 + m * 64) ^ aswz;
      bf16x8 ax = *(const bf16x8*)((const char*)s_x + ab);
      a0 = __builtin_amdgcn_mfma_f32_16x16x32_bf16(ax, wih_r[m],     a0, 0, 0, 0);
      a1 = __builtin_amdgcn_mfma_f32_16x16x32_bf16(ax, wih_r[8 + m], a1, 0, 0, 0);
    }

    // C+D: poll h(t) flags, read mailbox, stage s_h
    if (t > 0) {
      int fv;
      do {
        fv = __hip_atomic_load(flgp + (lane & 3), __ATOMIC_RELAXED, __HIP_MEMORY_SCOPE_AGENT);
      } while (!__all(fv >= t));
      asm volatile("" ::: "memory");

      const float* mbr = mb + (size_t)(t & 1) * (BATCH * HID) + (row_base + srow) * HID + scb;
      float v[8];
      #pragma unroll
      for (int jj = 0; jj < 4; ++jj) {
        union { unsigned long long u; float f[2]; } uu;
        uu.u = __hip_atomic_load((const unsigned long long*)(mbr + jj * 2),
                                 __ATOMIC_RELAXED, __HIP_MEMORY_SCOPE_AGENT);
        v[jj * 2]     = uu.f[0];
        v[jj * 2 + 1] = uu.f[1];
      }
      #pragma unroll
      for (int e = 0; e < 4; ++e) { v[e] *= mhs[0][e]; v[4 + e] *= mhs[1][e]; }
      bf16x8 hb;
      #pragma unroll
      for (int e = 0; e < 8; ++e) hb[e] = (__bf16)v[e];
      *(bf16x8*)((char*)s_h + soff) = hb;
    }

    // E: s_h visible to all
    asm volatile("s_waitcnt lgkmcnt(0)" ::: "memory");
    __builtin_amdgcn_s_barrier();

    // F: h-MFMAs
    #pragma unroll
    for (int m = 0; m < 8; ++m) {
      const int ab = (ab0 + m * 64) ^ aswz;
      bf16x8 ah = *(const bf16x8*)((const char*)s_h + ab);
      a0 = __builtin_amdgcn_mfma_f32_16x16x32_bf16(ah, whh_r[m],     a0, 0, 0, 0);
      a1 = __builtin_amdgcn_mfma_f32_16x16x32_bf16(ah, whh_r[8 + m], a1, 0, 0, 0);
    }

    // G: gates -> padded/swizzled LDS (C layout: col=l15, row=l4*4+e)
    #pragma unroll
    for (int tt = 0; tt < 2; ++tt) {
      const int gc = q * 64 + (w & 1) * 32 + tt * 16 + l15;
      const int pb = gc * 17 + 4 * (l4 ^ (gc & 3));
      const floatx4 av = tt ? a1 : a0;
      #pragma unroll
      for (int e = 0; e < 4; ++e) s_gates[pb + e] = av[e];
    }

    // H: gates visible
    asm volatile("s_waitcnt lgkmcnt(0)" ::: "memory");
    __builtin_amdgcn_s_barrier();

    // I: cell (fp32, in-register state)
    float o_[2];
    {
      const bool ract = (row_base + crow) < bszt;
      #pragma unroll
      for (int k = 0; k < 2; ++k) {
        const int colL = colL0 + 32 * k;
        float gq[4];
        #pragma unroll
        for (int qq = 0; qq < 4; ++qq) {
          const int gc = qq * 64 + colL;
          gq[qq] = s_gates[gc * 17 + 4 * ((crow >> 2) ^ (gc & 3)) + (crow & 3)];
        }
        const float iv = sigf(gq[0] + bb[0][k]);
        const float fv = sigf(gq[1] + bb[1][k]);
        const float gv = tanh_f(gq[2] + bb[2][k]);
        const float ov = sigf(gq[3] + bb[3][k]);
        const float cc = fv * c_[k] + iv * gv;
        const float hh = ov * tanh_f(cc);
        if (ract) { c_[k] = cc; h_[k] = hh; }
        o_[k] = ract ? hh : 0.0f;
      }
    }

    if (act_n) {
      // J: mailbox write h(t+1) (2 scalar relaxed stores, L2-resident)
      float* mbw = mb + (size_t)((t + 1) & 1) * (BATCH * HID) + (row_base + crow) * HID + s * 64;
      __hip_atomic_store(mbw + colL0,      h_[0], __ATOMIC_RELAXED, __HIP_MEMORY_SCOPE_AGENT);
      __hip_atomic_store(mbw + colL0 + 32, h_[1], __ATOMIC_RELAXED, __HIP_MEMORY_SCOPE_AGENT);
      // K: drain ONLY these (out stores not yet issued), then WG-barrier
      asm volatile("s_waitcnt vmcnt(0)" ::: "memory");
      __builtin_amdgcn_s_barrier();
      // L: post flag
      if (tid == 0)
        __hip_atomic_store(flgp + s, t + 1, __ATOMIC_RELAXED, __HIP_MEMORY_SCOPE_AGENT);
    }

    // M: out stores (after flag -> overlap partners' polls)
    {
      float* op = out + (size_t)t * (BATCH * HID) + (row_base + crow) * HID + s * 64;
      op[colL0] = o_[0]; op[colL0 + 32] = o_[1];
    }

    if (act_n) {
      // N: stage s_x(t+1) from prefetched regs
      float v[8];
      #pragma unroll
      for (int e = 0; e < 4; ++e) { v[e] = xpf0[e] * mxs[0][e]; v[4 + e] = xpf1[e] * mxs[1][e]; }
      bf16x8 xb;
      #pragma unroll
      for (int e = 0; e < 8; ++e) xb[e] = (__bf16)v[e];
      *(bf16x8*)((char*)s_x + soff) = xb;
      // O: s_x visible for next iter's x-MFMAs
      asm volatile("s_waitcnt lgkmcnt(0)" ::: "memory");
      __builtin_amdgcn_s_barrier();
    }
  }

  // epilogue: carry state (inactive rows hold last-active / initial values)
  hn_out[(row_base + crow) * HID + s * 64 + colL0]      = h_[0];
  hn_out[(row_base + crow) * HID + s * 64 + colL0 + 32] = h_[1];
  cn_out[(row_base + crow) * HID + s * 64 + colL0]      = c_[0];
  cn_out[(row_base + crow) * HID + s * 64 + colL0 + 32] = c_[1];
}

extern "C" void kernel_launch(void* const* d_in, const int* in_sizes, int n_in,
                              void* d_out, int out_size, void* d_ws, size_t ws_size,
                              hipStream_t stream) {
  const float* x      = (const float*)d_in[0];
  const float* h0     = (const float*)d_in[1];
  const float* c0     = (const float*)d_in[2];
  const float* mask_x = (const float*)d_in[3];
  const float* mask_h = (const float*)d_in[4];
  const float* W_ih   = (const float*)d_in[5];
  const float* W_hh   = (const float*)d_in[6];
  const float* b_ih   = (const float*)d_in[7];
  const float* b_hh   = (const float*)d_in[8];
  const int*   bs     = (const int*)d_in[9];

  float* out = (float*)d_out;
  float* hn  = out + (size_t)T_STEPS * BATCH * HID;
  float* cn  = hn + (size_t)BATCH * HID;

  int*   flg = (int*)d_ws;                       // 512 ints, zeroed per launch
  float* mb  = (float*)((char*)d_ws + 4096);     // 2 x B x H f32 mailbox (512 KB)

  init_ws<<<1, 512, 0, stream>>>(flg);
  lstm_s4<<<NGRP * NS, 512, 0, stream>>>(x, h0, c0, mask_x, mask_h, W_ih, W_hh,
                                         b_ih, b_hh, bs, out, hn, cn, flg, mb);
}

// Round 5
// 1802.259 us; speedup vs baseline: 1.0641x; 1.0641x over previous
//
#include <hip/hip_runtime.h>
#include <hip/hip_bf16.h>

#define T_STEPS 512
#define BATCH   256
#define DIM     256
#define HID     256
#define DEPTH   4    // X_proj ring depth (power of 2)

using bf16x8  = __attribute__((ext_vector_type(8))) __bf16;
using floatx4 = __attribute__((ext_vector_type(4))) float;

__device__ __forceinline__ float sigf(float x)   { return 1.0f / (1.0f + __expf(-x)); }
__device__ __forceinline__ float tanh_f(float x) { return 1.0f - 2.0f / (1.0f + __expf(2.0f * x)); }

__device__ __forceinline__ bf16x8 cvt8(const float* p) {
  floatx4 a = *(const floatx4*)p;
  floatx4 b = *(const floatx4*)(p + 4);
  bf16x8 r;
  r[0]=(__bf16)a[0]; r[1]=(__bf16)a[1]; r[2]=(__bf16)a[2]; r[3]=(__bf16)a[3];
  r[4]=(__bf16)b[0]; r[5]=(__bf16)b[1]; r[6]=(__bf16)b[2]; r[7]=(__bf16)b[3];
  return r;
}

__global__ void init_ws(int* __restrict__ bar) { bar[blockIdx.x * 512 + threadIdx.x] = 0; }

// 64 WGs x 512 thr. blockIdx = g + 16*role; group g = 16 batch rows.
// role 0,1: consumers (own h-cols [128p,128p+128), W_hh resident 128 VGPR).
// role 2,3: producers (X_proj for consumer p = role-2, W_ih resident).
// Producers run ahead through a DEPTH-slot f32 ring; consumers exchange h
// halves via one 8B bf16x4 agent-atomic + flag. All group members land on
// XCD g%8 under round-robin (perf heuristic only; protocol is placement-safe).
__global__ __launch_bounds__(512, 2) void lstm_pc(
    const float* __restrict__ x, const float* __restrict__ h0,
    const float* __restrict__ c0,
    const float* __restrict__ mask_x, const float* __restrict__ mask_h,
    const float* __restrict__ W_ih, const float* __restrict__ W_hh,
    const float* __restrict__ b_ih, const float* __restrict__ b_hh,
    const int* __restrict__ bs_g,
    float* __restrict__ out, float* __restrict__ hn_out, float* __restrict__ cn_out,
    int* __restrict__ flg, float* __restrict__ ring,
    unsigned long long* __restrict__ inbox) {

  const int tid  = threadIdx.x;
  const int g    = blockIdx.x & 15;
  const int role = blockIdx.x >> 4;
  const int p    = role & 1;
  const int row_base = g * 16;
  const int lane = tid & 63;
  const int w    = tid >> 6;     // wave 0..7
  const int l15  = lane & 15;
  const int l4   = lane >> 4;

  __shared__ alignas(16) __bf16 s_ab[16 * 256];   // 8 KB swizzled (h for consumer, x for producer)
  __shared__ int s_bs[T_STEPS];
  for (int i = tid; i < T_STEPS; i += 512) s_bs[i] = bs_g[i];
  __syncthreads();

  int* cons_flg_mine    = flg + (g * 2 + p) * 32;
  int* cons_flg_partner = flg + (g * 2 + (1 - p)) * 32;
  int* prod_flg_mine    = flg + 2048 + (g * 2 + p) * 32;
  float* ring_mine = ring + (size_t)(g * 2 + p) * (DEPTH * 8192);
  unsigned long long* inbox_mine    = inbox + (size_t)(g * 2 + p) * 1024;
  unsigned long long* inbox_partner = inbox + (size_t)(g * 2 + (1 - p)) * 1024;

  const int c_loc = w * 16 + l15;          // local col within the 128-col half

  if (role >= 2) {
    // ================= PRODUCER =================
    bf16x8 wih_r[4][8];
    #pragma unroll
    for (int q = 0; q < 4; ++q) {
      const size_t wr = (size_t)(q * HID + p * 128 + c_loc) * DIM;
      #pragma unroll
      for (int m = 0; m < 8; ++m) wih_r[q][m] = cvt8(W_ih + wr + m * 32 + l4 * 8);
    }
    float bias[4];
    #pragma unroll
    for (int q = 0; q < 4; ++q) {
      const int bc = q * HID + p * 128 + c_loc;
      bias[q] = b_ih[bc] + b_hh[bc];
    }
    const int srow = tid & 15, scb = (tid >> 4) * 8;
    floatx4 mx0 = *(const floatx4*)(mask_x + (row_base + srow) * DIM + scb);
    floatx4 mx1 = *(const floatx4*)(mask_x + (row_base + srow) * DIM + scb + 4);
    const int soff = (srow * 512 + scb * 2) ^ ((srow & 7) << 4);

    for (int t = 0; t < T_STEPS; ++t) {
      if (s_bs[t] <= row_base) break;                 // group retired forever
      if (t >= DEPTH) {                               // ring capacity
        const int tgt = t - (DEPTH - 1);
        while (__hip_atomic_load(cons_flg_mine, __ATOMIC_RELAXED, __HIP_MEMORY_SCOPE_AGENT) < tgt) {}
      }
      // stage xi(t) -> swizzled bf16 LDS
      const float* xp = x + ((size_t)t * BATCH + row_base + srow) * DIM + scb;
      floatx4 xa = *(const floatx4*)xp;
      floatx4 xb = *(const floatx4*)(xp + 4);
      bf16x8 xv;
      #pragma unroll
      for (int e = 0; e < 4; ++e) { xv[e] = (__bf16)(xa[e] * mx0[e]); xv[4 + e] = (__bf16)(xb[e] * mx1[e]); }
      *(bf16x8*)((char*)s_ab + soff) = xv;
      asm volatile("s_waitcnt lgkmcnt(0)" ::: "memory");
      __builtin_amdgcn_s_barrier();

      floatx4 a0, a1, a2, a3;
      a0 = a1 = a2 = a3 = (floatx4)(0.0f);
      #pragma unroll
      for (int m = 0; m < 8; ++m) {
        const int ab = (l15 * 512 + l4 * 16 + m * 64) ^ ((l15 & 7) << 4);
        bf16x8 ax = *(const bf16x8*)((const char*)s_ab + ab);
        a0 = __builtin_amdgcn_mfma_f32_16x16x32_bf16(ax, wih_r[0][m], a0, 0, 0, 0);
        a1 = __builtin_amdgcn_mfma_f32_16x16x32_bf16(ax, wih_r[1][m], a1, 0, 0, 0);
        a2 = __builtin_amdgcn_mfma_f32_16x16x32_bf16(ax, wih_r[2][m], a2, 0, 0, 0);
        a3 = __builtin_amdgcn_mfma_f32_16x16x32_bf16(ax, wih_r[3][m], a3, 0, 0, 0);
      }
      // ring store: [r][q][128] f32, + bias
      float* rs = ring_mine + (size_t)(t & (DEPTH - 1)) * 8192;
      #pragma unroll
      for (int e = 0; e < 4; ++e) {
        const int rb = (l4 * 4 + e) * 4;
        __hip_atomic_store(rs + (rb + 0) * 128 + c_loc, a0[e] + bias[0], __ATOMIC_RELAXED, __HIP_MEMORY_SCOPE_AGENT);
        __hip_atomic_store(rs + (rb + 1) * 128 + c_loc, a1[e] + bias[1], __ATOMIC_RELAXED, __HIP_MEMORY_SCOPE_AGENT);
        __hip_atomic_store(rs + (rb + 2) * 128 + c_loc, a2[e] + bias[2], __ATOMIC_RELAXED, __HIP_MEMORY_SCOPE_AGENT);
        __hip_atomic_store(rs + (rb + 3) * 128 + c_loc, a3[e] + bias[3], __ATOMIC_RELAXED, __HIP_MEMORY_SCOPE_AGENT);
      }
      asm volatile("s_waitcnt vmcnt(0)" ::: "memory");
      __builtin_amdgcn_s_barrier();                    // also fences WAR on s_ab
      if (tid == 0)
        __hip_atomic_store(prod_flg_mine, t + 1, __ATOMIC_RELAXED, __HIP_MEMORY_SCOPE_AGENT);
    }
    return;
  }

  // ================= CONSUMER =================
  const int c_own = p * 128 + c_loc;       // global h-col this lane computes
  bf16x8 whh_r[4][8];
  #pragma unroll
  for (int q = 0; q < 4; ++q) {
    const size_t wr = (size_t)(q * HID + c_own) * HID;
    #pragma unroll
    for (int m = 0; m < 8; ++m) whh_r[q][m] = cvt8(W_hh + wr + m * 32 + l4 * 8);
  }
  float mh_c[4], h_[4], c_[4];
  #pragma unroll
  for (int e = 0; e < 4; ++e) {
    const int grow = row_base + l4 * 4 + e;
    mh_c[e] = mask_h[grow * HID + c_own];
    h_[e]   = h0[grow * HID + c_own];
    c_[e]   = c0[grow * HID + c_own];
  }
  // stager (partner half): thread -> (col, 4 rows)
  const int sc_loc = tid >> 2;
  const int rq     = tid & 3;
  const int c_gs   = (1 - p) * 128 + sc_loc;
  float mh_s[4];
  #pragma unroll
  for (int e = 0; e < 4; ++e) mh_s[e] = mask_h[(row_base + rq * 4 + e) * HID + c_gs];

  // preload X_proj(0)
  while (__hip_atomic_load(prod_flg_mine, __ATOMIC_RELAXED, __HIP_MEMORY_SCOPE_AGENT) < 1) {}
  float xp_c[16];
  #pragma unroll
  for (int e = 0; e < 4; ++e)
    #pragma unroll
    for (int q = 0; q < 4; ++q)
      xp_c[e * 4 + q] = __hip_atomic_load(ring_mine + ((l4 * 4 + e) * 4 + q) * 128 + c_loc,
                                          __ATOMIC_RELAXED, __HIP_MEMORY_SCOPE_AGENT);

  for (int t = 0; t < T_STEPS; ++t) {
    const int bszt = s_bs[t];
    if (bszt <= row_base) {
      #pragma unroll
      for (int e = 0; e < 4; ++e)
        out[(size_t)t * (BATCH * HID) + (row_base + l4 * 4 + e) * HID + c_own] = 0.0f;
      continue;
    }
    const bool act_n = (t + 1 < T_STEPS) && (s_bs[t + 1] > row_base);

    // stage own half from registers
    #pragma unroll
    for (int e = 0; e < 4; ++e) {
      const int r = l4 * 4 + e;
      const int off = (r * 512 + c_own * 2) ^ ((r & 7) << 4);
      *(__bf16*)((char*)s_ab + off) = (__bf16)(h_[e] * mh_c[e]);
    }
    // stage partner half
    if (t == 0) {
      #pragma unroll
      for (int e = 0; e < 4; ++e) {
        const int r = rq * 4 + e;
        const float hv = h0[(row_base + r) * HID + c_gs] * mh_s[e];
        const int off = (r * 512 + c_gs * 2) ^ ((r & 7) << 4);
        *(__bf16*)((char*)s_ab + off) = (__bf16)hv;
      }
    } else {
      while (__hip_atomic_load(cons_flg_partner, __ATOMIC_RELAXED, __HIP_MEMORY_SCOPE_AGENT) < t) {}
      union { unsigned long long u; __bf16 b[4]; } pk;
      pk.u = __hip_atomic_load(inbox_mine + (size_t)(t & 1) * 512 + sc_loc * 4 + rq,
                               __ATOMIC_RELAXED, __HIP_MEMORY_SCOPE_AGENT);
      #pragma unroll
      for (int e = 0; e < 4; ++e) {
        const int r = rq * 4 + e;
        const float hv = (float)pk.b[e] * mh_s[e];
        const int off = (r * 512 + c_gs * 2) ^ ((r & 7) << 4);
        *(__bf16*)((char*)s_ab + off) = (__bf16)hv;
      }
    }
    // prefetch X_proj(t+1) (producer is ahead; poll normally hits first try)
    float xp_n[16];
    if (act_n) {
      while (__hip_atomic_load(prod_flg_mine, __ATOMIC_RELAXED, __HIP_MEMORY_SCOPE_AGENT) < t + 2) {}
      const float* rs = ring_mine + (size_t)((t + 1) & (DEPTH - 1)) * 8192;
      #pragma unroll
      for (int e = 0; e < 4; ++e)
        #pragma unroll
        for (int q = 0; q < 4; ++q)
          xp_n[e * 4 + q] = __hip_atomic_load(rs + ((l4 * 4 + e) * 4 + q) * 128 + c_loc,
                                              __ATOMIC_RELAXED, __HIP_MEMORY_SCOPE_AGENT);
    }

    asm volatile("s_waitcnt lgkmcnt(0)" ::: "memory");
    __builtin_amdgcn_s_barrier();

    // h @ W_hh^T : 4 gate tiles, K=256
    floatx4 a0, a1, a2, a3;
    a0 = a1 = a2 = a3 = (floatx4)(0.0f);
    #pragma unroll
    for (int m = 0; m < 8; ++m) {
      const int ab = (l15 * 512 + l4 * 16 + m * 64) ^ ((l15 & 7) << 4);
      bf16x8 ah = *(const bf16x8*)((const char*)s_ab + ab);
      a0 = __builtin_amdgcn_mfma_f32_16x16x32_bf16(ah, whh_r[0][m], a0, 0, 0, 0);
      a1 = __builtin_amdgcn_mfma_f32_16x16x32_bf16(ah, whh_r[1][m], a1, 0, 0, 0);
      a2 = __builtin_amdgcn_mfma_f32_16x16x32_bf16(ah, whh_r[2][m], a2, 0, 0, 0);
      a3 = __builtin_amdgcn_mfma_f32_16x16x32_bf16(ah, whh_r[3][m], a3, 0, 0, 0);
    }

    // cell, fully in-register (C layout: row = l4*4+e, col = l15 -> c_own)
    float o_[4];
    union { unsigned long long u; __bf16 b[4]; } hk;
    #pragma unroll
    for (int e = 0; e < 4; ++e) {
      const bool ract = (row_base + l4 * 4 + e) < bszt;
      const float iv = sigf(a0[e] + xp_c[e * 4 + 0]);
      const float fv = sigf(a1[e] + xp_c[e * 4 + 1]);
      const float gv = tanh_f(a2[e] + xp_c[e * 4 + 2]);
      const float ov = sigf(a3[e] + xp_c[e * 4 + 3]);
      const float cc = fv * c_[e] + iv * gv;
      const float hh = ov * tanh_f(cc);
      if (ract) { c_[e] = cc; h_[e] = hh; }
      o_[e] = ract ? hh : 0.0f;
      hk.b[e] = (__bf16)h_[e];
    }

    if (act_n) {
      // send my half to partner: one 8B agent-atomic per lane
      __hip_atomic_store(inbox_partner + (size_t)((t + 1) & 1) * 512 + c_loc * 4 + l4, hk.u,
                         __ATOMIC_RELAXED, __HIP_MEMORY_SCOPE_AGENT);
      asm volatile("s_waitcnt vmcnt(0)" ::: "memory");
      __builtin_amdgcn_s_barrier();                    // all sends acked; also fences s_ab WAR
      if (tid == 0)
        __hip_atomic_store(cons_flg_mine, t + 1, __ATOMIC_RELAXED, __HIP_MEMORY_SCOPE_AGENT);
    }

    // out stores after the flag (drained by NEXT step's vmcnt, off critical path)
    #pragma unroll
    for (int e = 0; e < 4; ++e)
      out[(size_t)t * (BATCH * HID) + (row_base + l4 * 4 + e) * HID + c_own] = o_[e];

    if (act_n) {
      #pragma unroll
      for (int i = 0; i < 16; ++i) xp_c[i] = xp_n[i];
    }
  }

  // epilogue
  #pragma unroll
  for (int e = 0; e < 4; ++e) {
    const int grow = row_base + l4 * 4 + e;
    hn_out[grow * HID + c_own] = h_[e];
    cn_out[grow * HID + c_own] = c_[e];
  }
}

extern "C" void kernel_launch(void* const* d_in, const int* in_sizes, int n_in,
                              void* d_out, int out_size, void* d_ws, size_t ws_size,
                              hipStream_t stream) {
  const float* x      = (const float*)d_in[0];
  const float* h0     = (const float*)d_in[1];
  const float* c0     = (const float*)d_in[2];
  const float* mask_x = (const float*)d_in[3];
  const float* mask_h = (const float*)d_in[4];
  const float* W_ih   = (const float*)d_in[5];
  const float* W_hh   = (const float*)d_in[6];
  const float* b_ih   = (const float*)d_in[7];
  const float* b_hh   = (const float*)d_in[8];
  const int*   bs     = (const int*)d_in[9];

  float* out = (float*)d_out;
  float* hn  = out + (size_t)T_STEPS * BATCH * HID;
  float* cn  = hn + (size_t)BATCH * HID;

  int*   flg  = (int*)d_ws;                                    // 4096 ints (16 KB)
  float* ring = (float*)((char*)d_ws + 16384);                 // 32 x DEPTH x 8192 f32 = 4 MB
  unsigned long long* inbox =
      (unsigned long long*)((char*)d_ws + 16384 + 4194304);    // 32 x 1024 ull = 256 KB

  init_ws<<<8, 512, 0, stream>>>(flg);
  lstm_pc<<<64, 512, 0, stream>>>(x, h0, c0, mask_x, mask_h, W_ih, W_hh,
                                  b_ih, b_hh, bs, out, hn, cn, flg, ring, inbox);
}